// Round 1
// baseline (317.783 us; speedup 1.0000x reference)
//
#include <hip/hip_runtime.h>
#include <math.h>

// SegmentedTensorSquareSelfInteraction on MI355X (gfx950)
// N=32768, MUL0=256, MUL1=128, G=64, INV_DIM=448, used gates=576, out=(N,640) fp32
//
// Pipeline (all bf16 MFMA GEMMs, fp32 accumulate, B pre-transposed+cast):
//  1. wcast : W1/W2[:, :576]/Wl0/Wl1 -> bf16 transposed (padded to mult of 128 cols)
//  2. prep  : x -> s_all bf16 (N,448)  [s copy + tensor-square invariants t0]
//  3. gemm<0>: h = silu(s_all @ W1 / sqrt448)        -> HU bf16 (N,448)
//  4. gemm<1>: gates = h @ W2[:,:576] / sqrt448      -> GATES bf16 (N,576)
//  5. gate  : u = s_all*g0 -> HU (reuse); wmat[(n,i),m] = v[n,m,i]*g1o[m] -> WMAT
//  6. gemm<2>: o0 = u @ Wl0 / sqrt448                -> d_out[:, :256] fp32 (pre-LN)
//  7. gemm<2>: o1' = wmat @ Wl1 / sqrt128            -> O1 fp32 (3N,128)
//  8. norm  : LayerNorm(o0) in-place; RMS-norm o1 -> d_out[:, 256:640]
//
// ws usage: 122,929,152 bytes peak (O1 overlays SALL/HU after they die).

typedef float floatx4 __attribute__((ext_vector_type(4)));
typedef __bf16 bf16x8 __attribute__((ext_vector_type(8)));

__device__ __forceinline__ unsigned short f2bf(float f) {
    union { float f; unsigned u; } v; v.f = f;
    unsigned r = v.u + 0x7FFFu + ((v.u >> 16) & 1u);  // round-to-nearest-even
    return (unsigned short)(r >> 16);
}
__device__ __forceinline__ float bf2f(unsigned short u) {
    union { unsigned u; float f; } v; v.u = ((unsigned)u) << 16; return v.f;
}

// ---------------------------------------------------------------- weight cast
// Dest-indexed: writes coalesced, reads strided (weights are L2-resident, tiny).
__global__ __launch_bounds__(256) void wcast_kernel(
    const float* __restrict__ W1, const float* __restrict__ W2,
    const float* __restrict__ Wl0, const float* __restrict__ Wl1,
    unsigned short* __restrict__ W1T, unsigned short* __restrict__ W2T,
    unsigned short* __restrict__ Wl0T, unsigned short* __restrict__ Wl1T)
{
    int idx = blockIdx.x * 256 + threadIdx.x;
    if (idx < 229376) {                      // W1T: 512 x 448 (rows 448..511 zero)
        int j = idx / 448, k = idx - j * 448;
        float v = (j < 448) ? W1[k * 448 + j] : 0.f;
        W1T[idx] = f2bf(v);
    } else if (idx < 229376 + 286720) {      // W2T: 640 x 448 (rows 576..639 zero)
        int r = idx - 229376;
        int j = r / 448, k = r - j * 448;
        float v = (j < 576) ? W2[k * 832 + j] : 0.f;
        W2T[r] = f2bf(v);
    } else if (idx < 229376 + 286720 + 114688) {  // Wl0T: 256 x 448
        int r = idx - (229376 + 286720);
        int j = r / 448, k = r - j * 448;
        Wl0T[r] = f2bf(Wl0[k * 256 + j]);
    } else {                                 // Wl1T: 128 x 128
        int r = idx - (229376 + 286720 + 114688);
        int j = r / 128, m = r - j * 128;
        Wl1T[r] = f2bf(Wl1[m * 128 + j]);
    }
}

// ---------------------------------------------------------------- prep: s_all
// 128 work units per node: 64 float4-copy units (s part), 64 group units (t0).
__global__ __launch_bounds__(256) void prep_kernel(
    const float* __restrict__ x, unsigned short* __restrict__ sall)
{
    int idx = blockIdx.x * 256 + threadIdx.x;   // N*128 total
    int n = idx >> 7, r = idx & 127;
    const float* xr = x + n * 640;
    if (r < 64) {
        float4 s = *(const float4*)(xr + 4 * r);
        unsigned short* o = sall + n * 448 + 4 * r;
        uint2 p;
        p.x = (unsigned)f2bf(s.x) | ((unsigned)f2bf(s.y) << 16);
        p.y = (unsigned)f2bf(s.z) | ((unsigned)f2bf(s.w) << 16);
        *(uint2*)o = p;
    } else {
        int g = r - 64;
        const float2* vg = (const float2*)(xr + 256 + 6 * g);
        float2 p0 = vg[0], p1 = vg[1], p2 = vg[2];
        float ax = p0.x, ay = p0.y, az = p1.x;
        float bx = p1.y, by = p2.x, bz = p2.y;
        float aa = ax*ax + ay*ay + az*az;
        float ab = ax*bx + ay*by + az*bz;
        float bb = bx*bx + by*by + bz*bz;
        const float ISQ3 = 0.57735026918962576f;
        const float SQ2  = 1.41421356237309505f;
        unsigned short* o = sall + n * 448 + 256 + 3 * g;
        o[0] = f2bf(aa * ISQ3);
        o[1] = f2bf(SQ2 * ab * ISQ3);
        o[2] = f2bf(bb * ISQ3);
    }
}

// ---------------------------------------------------------------- GEMM (bf16, B^T)
// C[M,Nc] = A[M,K] @ B[K,Nc] * scale, with Bt = B^T (NcPad x K) zero-padded.
// Tile 128x128xBK32, 4 waves in 2x2, each wave 4x4 tiles of 16x16x32 MFMA.
// MODE 0: silu -> bf16 | MODE 1: bf16 | MODE 2: fp32
template<int MODE>
__global__ __launch_bounds__(256, 2)
void gemm_bt(const unsigned short* __restrict__ A,
             const unsigned short* __restrict__ Bt,
             unsigned short* __restrict__ outB,
             float* __restrict__ outF,
             int K, int NcTrue, int ldc, float scale)
{
    alignas(16) __shared__ unsigned short As[128 * 32];
    alignas(16) __shared__ unsigned short Bs[128 * 32];
    const int tid  = threadIdx.x;
    const int lane = tid & 63;
    const int wid  = tid >> 6;
    const int bM   = blockIdx.x * 128;
    const int bN   = blockIdx.y * 128;
    const int wm   = (wid >> 1) * 64;
    const int wn   = (wid & 1) * 64;
    const int l15  = lane & 15;
    const int quad = lane >> 4;

    // staging: thread t loads rows r0 and r0+64, 8 bf16 (16B) chunks
    const int r0 = tid >> 2;
    const int c8 = (tid & 3) * 8;
    const unsigned short* Ag = A  + (bM + r0) * K + c8;
    const unsigned short* Bg = Bt + (bN + r0) * K + c8;
    const int rowOff = 64 * K;

    floatx4 acc[4][4] = {};

    for (int k0 = 0; k0 < K; k0 += 32) {
        uint4 a0 = *(const uint4*)(Ag + k0);
        uint4 a1 = *(const uint4*)(Ag + rowOff + k0);
        uint4 b0 = *(const uint4*)(Bg + k0);
        uint4 b1 = *(const uint4*)(Bg + rowOff + k0);
        __syncthreads();
        *(uint4*)&As[r0 * 32 + c8]        = a0;
        *(uint4*)&As[(r0 + 64) * 32 + c8] = a1;
        *(uint4*)&Bs[r0 * 32 + c8]        = b0;
        *(uint4*)&Bs[(r0 + 64) * 32 + c8] = b1;
        __syncthreads();

        const bf16x8* Ap = (const bf16x8*)As;
        const bf16x8* Bp = (const bf16x8*)Bs;
        bf16x8 af[4], bfv[4];
        #pragma unroll
        for (int tm = 0; tm < 4; ++tm) af[tm]  = Ap[(wm + tm * 16 + l15) * 4 + quad];
        #pragma unroll
        for (int tn = 0; tn < 4; ++tn) bfv[tn] = Bp[(wn + tn * 16 + l15) * 4 + quad];
        #pragma unroll
        for (int tm = 0; tm < 4; ++tm)
            #pragma unroll
            for (int tn = 0; tn < 4; ++tn)
                acc[tm][tn] = __builtin_amdgcn_mfma_f32_16x16x32_bf16(
                    af[tm], bfv[tn], acc[tm][tn], 0, 0, 0);
    }

    // epilogue: C/D layout col = lane&15, row = quad*4 + r (verified m89/m91)
    #pragma unroll
    for (int tm = 0; tm < 4; ++tm) {
        const int rowBase = bM + wm + tm * 16 + quad * 4;
        #pragma unroll
        for (int tn = 0; tn < 4; ++tn) {
            const int colBase = bN + wn + tn * 16;
            if (colBase >= NcTrue) continue;      // padded cols (uniform per tile)
            const int col = colBase + l15;
            #pragma unroll
            for (int r = 0; r < 4; ++r) {
                float v = acc[tm][tn][r] * scale;
                if (MODE == 0) {
                    v = v / (1.f + __expf(-v));   // silu
                    outB[(rowBase + r) * ldc + col] = f2bf(v);
                } else if (MODE == 1) {
                    outB[(rowBase + r) * ldc + col] = f2bf(v);
                } else {
                    outF[(rowBase + r) * ldc + col] = v;
                }
            }
        }
    }
}

// ---------------------------------------------------------------- gating
__global__ __launch_bounds__(256) void gate_kernel(
    const float* __restrict__ x, const unsigned short* __restrict__ sall,
    const unsigned short* __restrict__ gates,
    unsigned short* __restrict__ u, unsigned short* __restrict__ wmat)
{
    const int n = blockIdx.x;
    const int t = threadIdx.x;
    const unsigned short* g = gates + n * 576;
    const unsigned short* s = sall + n * 448;
    unsigned short* un = u + n * 448;
    for (int j = t; j < 448; j += 256)
        un[j] = f2bf(bf2f(s[j]) * bf2f(g[j]));
    const float* xv = x + n * 640 + 256;
    unsigned short* wn = wmat + n * 384;     // layout: [i][m], row (n*3+i)
    for (int idx = t; idx < 384; idx += 256) {
        int i = idx >> 7, m = idx & 127;
        wn[idx] = f2bf(xv[3 * m + i] * bf2f(g[448 + m]));
    }
}

// ---------------------------------------------------------------- norms
__global__ __launch_bounds__(256) void norm_kernel(
    float* __restrict__ out, const float* __restrict__ o1)
{
    const int n = blockIdx.x;
    const int t = threadIdx.x;
    float* o0 = out + n * 640;
    const float* p1 = o1 + n * 384;

    float v0 = o0[t];                         // 256 elems, one per thread
    float a0 = p1[t];
    float a1 = (t < 128) ? p1[256 + t] : 0.f;
    float s1v = v0, s2v = v0 * v0, q = a0 * a0 + a1 * a1;

    #pragma unroll
    for (int off = 32; off > 0; off >>= 1) {
        s1v += __shfl_down(s1v, off);
        s2v += __shfl_down(s2v, off);
        q   += __shfl_down(q, off);
    }
    __shared__ float red[3][4];
    const int wid = t >> 6, lane = t & 63;
    if (lane == 0) { red[0][wid] = s1v; red[1][wid] = s2v; red[2][wid] = q; }
    __syncthreads();
    float tsum = red[0][0] + red[0][1] + red[0][2] + red[0][3];
    float tsq  = red[1][0] + red[1][1] + red[1][2] + red[1][3];
    float tq   = red[2][0] + red[2][1] + red[2][2] + red[2][3];

    float mu   = tsum * (1.f / 256.f);
    float var  = tsq * (1.f / 256.f) - mu * mu;
    float rln  = rsqrtf(var + 1e-6f);
    float rrms = rsqrtf(tq * (1.f / 384.f) + 1e-6f);

    o0[t] = (v0 - mu) * rln;
    for (int idx = t; idx < 384; idx += 256) {    // out pos 3k+i; o1 row-(n,i), col k
        int k = idx / 3, i = idx - 3 * k;
        out[n * 640 + 256 + idx] = p1[i * 128 + k] * rrms;
    }
}

// ---------------------------------------------------------------- launch
extern "C" void kernel_launch(void* const* d_in, const int* in_sizes, int n_in,
                              void* d_out, int out_size, void* d_ws, size_t ws_size,
                              hipStream_t stream) {
    const float* x   = (const float*)d_in[0];
    const float* W1  = (const float*)d_in[1];
    const float* W2  = (const float*)d_in[2];
    const float* Wl0 = (const float*)d_in[3];
    const float* Wl1 = (const float*)d_in[4];
    float* out = (float*)d_out;
    char* ws = (char*)d_ws;

    unsigned short* SALL  = (unsigned short*)(ws + 0);            // 29,360,128 B
    unsigned short* HU    = (unsigned short*)(ws + 29360128);     // 29,360,128 B (h, then u)
    unsigned short* GATES = (unsigned short*)(ws + 58720256);     // 37,748,736 B
    unsigned short* WMAT  = (unsigned short*)(ws + 96468992);     // 25,165,824 B
    float*          O1    = (float*)(ws + 0);                     // 50,331,648 B (overlays dead SALL/HU)
    unsigned short* W1T   = (unsigned short*)(ws + 121634816);    //    458,752 B
    unsigned short* W2T   = (unsigned short*)(ws + 122093568);    //    573,440 B
    unsigned short* Wl0T  = (unsigned short*)(ws + 122667008);    //    229,376 B
    unsigned short* Wl1T  = (unsigned short*)(ws + 122896384);    //     32,768 B
    // peak ws: 122,929,152 bytes

    const float s1 = 0.047245559f;   // 1/sqrt(448)
    const float s2 = 0.088388348f;   // 1/sqrt(128)

    wcast_kernel<<<dim3(2528), dim3(256), 0, stream>>>(W1, W2, Wl0, Wl1, W1T, W2T, Wl0T, Wl1T);
    prep_kernel<<<dim3(16384), dim3(256), 0, stream>>>(x, SALL);
    gemm_bt<0><<<dim3(256, 4), dim3(256), 0, stream>>>(SALL, W1T, HU, nullptr, 448, 448, 448, s1);
    gemm_bt<1><<<dim3(256, 5), dim3(256), 0, stream>>>(HU, W2T, GATES, nullptr, 448, 576, 576, s1);
    gate_kernel<<<dim3(32768), dim3(256), 0, stream>>>(x, SALL, GATES, HU, WMAT);
    gemm_bt<2><<<dim3(256, 2), dim3(256), 0, stream>>>(HU, Wl0T, nullptr, out, 448, 256, 640, s1);
    gemm_bt<2><<<dim3(768, 1), dim3(256), 0, stream>>>(WMAT, Wl1T, nullptr, O1, 128, 128, 128, s2);
    norm_kernel<<<dim3(32768), dim3(256), 0, stream>>>(out, O1);
}